// Round 1
// baseline (1659.248 us; speedup 1.0000x reference)
//
#include <hip/hip_runtime.h>

// ---------------------------------------------------------------------------
// GraphElementNetwork forward:
//   h0 = encMLP(node_feat)                      [N]
//   h1 = softmax_agg(h0, edge_dist)             [N]   (exp w/o max-sub: exact in R)
//   eh = euMLP([edge_feat, h1[src], h1[dst]])   [E]
//   agg = segsum(eh, dst); s2 = segsum(exp(eh), dst)   (fused into edge pass)
//   h2 = nuMLP([agg, h1])                       [N]
//   h3 = segsum(exp(eh)*h2[src], dst) / s2      [N]
//   out = decMLP(h3)                            [N]
// ---------------------------------------------------------------------------

__device__ __forceinline__ void atomAddF(float* p, float v) {
    unsafeAtomicAdd(p, v);  // HW global_atomic_add_f32 on gfx950
}

__global__ void k_zero(float* __restrict__ p, int n) {
    int i = blockIdx.x * blockDim.x + threadIdx.x;
    if (i < n) p[i] = 0.f;
}

// --- node encoder: 128 -> 64 -> 1, full W1 (32KB) staged in LDS ------------
__global__ void __launch_bounds__(256) k_enc(
    const float* __restrict__ X, const float* __restrict__ W1,
    const float* __restrict__ B1, const float* __restrict__ W2,
    const float* __restrict__ B2, float* __restrict__ H0, int n)
{
    __shared__ float4 w1s[2048];  // [k][j4] : W1[k][4j..4j+3]
    for (int t = threadIdx.x; t < 2048; t += blockDim.x)
        w1s[t] = reinterpret_cast<const float4*>(W1)[t];
    __syncthreads();

    int i = blockIdx.x * blockDim.x + threadIdx.x;
    if (i >= n) return;

    const float4* xp = reinterpret_cast<const float4*>(X) + (size_t)i * 32;

    float acc[64];
    #pragma unroll
    for (int j = 0; j < 64; ++j) acc[j] = B1[j];

    for (int k4 = 0; k4 < 32; ++k4) {
        float4 xv = xp[k4];
        #pragma unroll
        for (int kk = 0; kk < 4; ++kk) {
            float x = (&xv.x)[kk];
            const float4* wrow = &w1s[(k4 * 4 + kk) * 16];
            #pragma unroll
            for (int j4 = 0; j4 < 16; ++j4) {
                float4 w = wrow[j4];
                acc[j4*4+0] = fmaf(x, w.x, acc[j4*4+0]);
                acc[j4*4+1] = fmaf(x, w.y, acc[j4*4+1]);
                acc[j4*4+2] = fmaf(x, w.z, acc[j4*4+2]);
                acc[j4*4+3] = fmaf(x, w.w, acc[j4*4+3]);
            }
        }
    }
    float o = B2[0];
    #pragma unroll
    for (int j = 0; j < 64; ++j)
        o = fmaf(fmaxf(acc[j], 0.f), W2[j], o);
    H0[i] = fmaxf(o, 0.f);
}

// --- edge softmax-agg #1: s1[d] += exp(dist); num1[d] += exp(dist)*h0[s] ---
__global__ void __launch_bounds__(256) k_agg1(
    const float* __restrict__ DIST, const int* __restrict__ SRC,
    const int* __restrict__ DST, const float* __restrict__ H0,
    float* __restrict__ S1, float* __restrict__ NUM1, int e)
{
    int t = blockIdx.x * blockDim.x + threadIdx.x;
    int i0 = t * 4;
    if (i0 >= e) return;
    if (i0 + 3 < e) {
        float4 dv = reinterpret_cast<const float4*>(DIST)[t];
        int4 sv = reinterpret_cast<const int4*>(SRC)[t];
        int4 tv = reinterpret_cast<const int4*>(DST)[t];
        #pragma unroll
        for (int u = 0; u < 4; ++u) {
            float ev = __expf((&dv.x)[u]);
            int s = (&sv.x)[u], d = (&tv.x)[u];
            atomAddF(&S1[d], ev);
            atomAddF(&NUM1[d], ev * H0[s]);
        }
    } else {
        for (int i = i0; i < e; ++i) {
            float ev = __expf(DIST[i]);
            atomAddF(&S1[DST[i]], ev);
            atomAddF(&NUM1[DST[i]], ev * H0[SRC[i]]);
        }
    }
}

__global__ void k_div(const float* __restrict__ NUM, const float* __restrict__ S,
                      float* __restrict__ H, int n) {
    int i = blockIdx.x * blockDim.x + threadIdx.x;
    if (i < n) {
        float s = S[i];
        H[i] = (s != 0.f) ? NUM[i] / s : 0.f;
    }
}

// --- edge MLP 3->64->1, 4 edges/thread; fused agg & s2 accumulation --------
__global__ void __launch_bounds__(256) k_edge(
    const float* __restrict__ EF, const int* __restrict__ SRC,
    const int* __restrict__ DST, const float* __restrict__ H1,
    const float* __restrict__ W1, const float* __restrict__ B1,
    const float* __restrict__ W2, const float* __restrict__ B2,
    float* __restrict__ E2, float* __restrict__ AGG, float* __restrict__ S2, int e)
{
    __shared__ float4 wA[16], wB[16], wC[16], wD[16], wV[16];  // SoA weights
    if (threadIdx.x < 16) {
        int j4 = threadIdx.x;
        const float4* W1v = reinterpret_cast<const float4*>(W1);
        wA[j4] = W1v[j4];        // W1[0][.]
        wB[j4] = W1v[16 + j4];   // W1[1][.]
        wC[j4] = W1v[32 + j4];   // W1[2][.]
        wD[j4] = reinterpret_cast<const float4*>(B1)[j4];
        wV[j4] = reinterpret_cast<const float4*>(W2)[j4];
    }
    __syncthreads();
    const float b2 = B2[0];

    int t = blockIdx.x * blockDim.x + threadIdx.x;
    int i0 = t * 4;
    if (i0 >= e) return;

    if (i0 + 3 < e) {
        float4 efv = reinterpret_cast<const float4*>(EF)[t];
        int4 sv = reinterpret_cast<const int4*>(SRC)[t];
        int4 dv = reinterpret_cast<const int4*>(DST)[t];
        float hs[4], hd[4], o[4];
        #pragma unroll
        for (int u = 0; u < 4; ++u) {
            hs[u] = H1[(&sv.x)[u]];
            hd[u] = H1[(&dv.x)[u]];
            o[u] = b2;
        }
        #pragma unroll
        for (int j4 = 0; j4 < 16; ++j4) {
            float4 a = wA[j4], b = wB[j4], c = wC[j4], d = wD[j4], v = wV[j4];
            #pragma unroll
            for (int u = 0; u < 4; ++u) {
                float x0 = (&efv.x)[u];
                float t0 = fmaf(x0, a.x, fmaf(hs[u], b.x, fmaf(hd[u], c.x, d.x)));
                o[u] = fmaf(fmaxf(t0, 0.f), v.x, o[u]);
                float t1 = fmaf(x0, a.y, fmaf(hs[u], b.y, fmaf(hd[u], c.y, d.y)));
                o[u] = fmaf(fmaxf(t1, 0.f), v.y, o[u]);
                float t2 = fmaf(x0, a.z, fmaf(hs[u], b.z, fmaf(hd[u], c.z, d.z)));
                o[u] = fmaf(fmaxf(t2, 0.f), v.z, o[u]);
                float t3 = fmaf(x0, a.w, fmaf(hs[u], b.w, fmaf(hd[u], c.w, d.w)));
                o[u] = fmaf(fmaxf(t3, 0.f), v.w, o[u]);
            }
        }
        float4 e2v;
        #pragma unroll
        for (int u = 0; u < 4; ++u) {
            float eh = fmaxf(o[u], 0.f);
            float ex = __expf(eh);
            (&e2v.x)[u] = ex;
            int d = (&dv.x)[u];
            atomAddF(&AGG[d], eh);
            atomAddF(&S2[d], ex);
        }
        reinterpret_cast<float4*>(E2)[t] = e2v;
    } else {
        for (int i = i0; i < e; ++i) {
            float x0 = EF[i];
            int s = SRC[i], d = DST[i];
            float h_s = H1[s], h_d = H1[d];
            float o = b2;
            for (int j = 0; j < 64; ++j) {
                float aj = fmaf(x0, W1[j], fmaf(h_s, W1[64+j], fmaf(h_d, W1[128+j], B1[j])));
                o = fmaf(fmaxf(aj, 0.f), W2[j], o);
            }
            float eh = fmaxf(o, 0.f);
            float ex = __expf(eh);
            E2[i] = ex;
            atomAddF(&AGG[d], eh);
            atomAddF(&S2[d], ex);
        }
    }
}

// --- node update MLP: 2 -> 64 -> 1 -----------------------------------------
__global__ void k_nu(const float* __restrict__ AGG, const float* __restrict__ H1,
                     const float* __restrict__ W1, const float* __restrict__ B1,
                     const float* __restrict__ W2, const float* __restrict__ B2,
                     float* __restrict__ H2, int n)
{
    int i = blockIdx.x * blockDim.x + threadIdx.x;
    if (i >= n) return;
    float x0 = AGG[i], x1 = H1[i];
    float o = B2[0];
    #pragma unroll
    for (int j = 0; j < 64; ++j) {
        float a = fmaf(x0, W1[j], fmaf(x1, W1[64 + j], B1[j]));
        o = fmaf(fmaxf(a, 0.f), W2[j], o);
    }
    H2[i] = fmaxf(o, 0.f);
}

// --- edge softmax-agg #2 numerator: num2[d] += e2 * h2[s] ------------------
__global__ void __launch_bounds__(256) k_agg2(
    const float* __restrict__ E2, const int* __restrict__ SRC,
    const int* __restrict__ DST, const float* __restrict__ H2,
    float* __restrict__ NUM2, int e)
{
    int t = blockIdx.x * blockDim.x + threadIdx.x;
    int i0 = t * 4;
    if (i0 >= e) return;
    if (i0 + 3 < e) {
        float4 ev = reinterpret_cast<const float4*>(E2)[t];
        int4 sv = reinterpret_cast<const int4*>(SRC)[t];
        int4 dv = reinterpret_cast<const int4*>(DST)[t];
        #pragma unroll
        for (int u = 0; u < 4; ++u)
            atomAddF(&NUM2[(&dv.x)[u]], (&ev.x)[u] * H2[(&sv.x)[u]]);
    } else {
        for (int i = i0; i < e; ++i)
            atomAddF(&NUM2[DST[i]], E2[i] * H2[SRC[i]]);
    }
}

// --- final: h3 = num2/s2; decoder 1 -> 64 -> 1 -----------------------------
__global__ void k_final(const float* __restrict__ NUM2, const float* __restrict__ S2,
                        const float* __restrict__ W1, const float* __restrict__ B1,
                        const float* __restrict__ W2, const float* __restrict__ B2,
                        float* __restrict__ OUT, int n)
{
    int i = blockIdx.x * blockDim.x + threadIdx.x;
    if (i >= n) return;
    float s = S2[i];
    float x = (s != 0.f) ? NUM2[i] / s : 0.f;
    float o = B2[0];
    #pragma unroll
    for (int j = 0; j < 64; ++j) {
        float a = fmaf(x, W1[j], B1[j]);
        o = fmaf(fmaxf(a, 0.f), W2[j], o);
    }
    OUT[i] = fmaxf(o, 0.f);
}

extern "C" void kernel_launch(void* const* d_in, const int* in_sizes, int n_in,
                              void* d_out, int out_size, void* d_ws, size_t ws_size,
                              hipStream_t stream)
{
    const float* node_feat = (const float*)d_in[0];
    const float* edge_feat = (const float*)d_in[1];
    const float* edge_dist = (const float*)d_in[2];
    const int*   src       = (const int*)d_in[3];
    const int*   dst       = (const int*)d_in[4];
    const float* enc_w1 = (const float*)d_in[5];
    const float* enc_b1 = (const float*)d_in[6];
    const float* enc_w2 = (const float*)d_in[7];
    const float* enc_b2 = (const float*)d_in[8];
    const float* nu_w1  = (const float*)d_in[9];
    const float* nu_b1  = (const float*)d_in[10];
    const float* nu_w2  = (const float*)d_in[11];
    const float* nu_b2  = (const float*)d_in[12];
    const float* eu_w1  = (const float*)d_in[13];
    const float* eu_b1  = (const float*)d_in[14];
    const float* eu_w2  = (const float*)d_in[15];
    const float* eu_b2  = (const float*)d_in[16];
    const float* dec_w1 = (const float*)d_in[17];
    const float* dec_b1 = (const float*)d_in[18];
    const float* dec_w2 = (const float*)d_in[19];
    const float* dec_b2 = (const float*)d_in[20];

    const int n = in_sizes[0] / 128;
    const int e = in_sizes[1];

    // workspace layout (floats): h0,h1,h2 | s1,num1,agg,s2,num2 (zeroed) | e2[E]
    float* ws   = (float*)d_ws;
    float* h0   = ws;
    float* h1   = ws + (size_t)1 * n;
    float* h2   = ws + (size_t)2 * n;
    float* s1   = ws + (size_t)3 * n;
    float* num1 = ws + (size_t)4 * n;
    float* agg  = ws + (size_t)5 * n;
    float* s2   = ws + (size_t)6 * n;
    float* num2 = ws + (size_t)7 * n;
    float* e2   = ws + (size_t)8 * n;

    const int B = 256;
    const int e4 = (e + 3) / 4;

    hipLaunchKernelGGL(k_zero, dim3((5 * n + B - 1) / B), dim3(B), 0, stream,
                       s1, 5 * n);
    hipLaunchKernelGGL(k_enc, dim3((n + B - 1) / B), dim3(B), 0, stream,
                       node_feat, enc_w1, enc_b1, enc_w2, enc_b2, h0, n);
    hipLaunchKernelGGL(k_agg1, dim3((e4 + B - 1) / B), dim3(B), 0, stream,
                       edge_dist, src, dst, h0, s1, num1, e);
    hipLaunchKernelGGL(k_div, dim3((n + B - 1) / B), dim3(B), 0, stream,
                       num1, s1, h1, n);
    hipLaunchKernelGGL(k_edge, dim3((e4 + B - 1) / B), dim3(B), 0, stream,
                       edge_feat, src, dst, h1, eu_w1, eu_b1, eu_w2, eu_b2,
                       e2, agg, s2, e);
    hipLaunchKernelGGL(k_nu, dim3((n + B - 1) / B), dim3(B), 0, stream,
                       agg, h1, nu_w1, nu_b1, nu_w2, nu_b2, h2, n);
    hipLaunchKernelGGL(k_agg2, dim3((e4 + B - 1) / B), dim3(B), 0, stream,
                       e2, src, dst, h2, num2, e);
    hipLaunchKernelGGL(k_final, dim3((n + B - 1) / B), dim3(B), 0, stream,
                       num2, s2, dec_w1, dec_b1, dec_w2, dec_b2, (float*)d_out, n);
}

// Round 2
// 612.284 us; speedup vs baseline: 2.7099x; 2.7099x over previous
//
#include <hip/hip_runtime.h>

// ---------------------------------------------------------------------------
// GraphElementNetwork forward, atomic-free main path:
//   Edges are coarse-bucketed by dst>>SHIFT (bucket width 128 dst values).
//   All segment reductions then run per-bucket with LDS accumulators
//   (CU-local ds_add_f32), eliminating ~32M device-scope fabric atomics
//   that dominated round 1 (20 G atomics/s wall, WRITE_SIZE 424 MB/pass).
// ---------------------------------------------------------------------------

#define NHB 1024  // histogram / scatter blocks

// ============================ bucketing ====================================

__global__ void __launch_bounds__(256) k_chist(
    const int* __restrict__ DST, int* __restrict__ hist,
    int e, int nbkt, int shift, int epb)
{
    __shared__ int lh[1024];
    for (int c = threadIdx.x; c < nbkt; c += blockDim.x) lh[c] = 0;
    __syncthreads();
    int b = blockIdx.x;
    int i0 = b * epb, i1 = min(i0 + epb, e);
    for (int i = i0 + threadIdx.x; i < i1; i += blockDim.x)
        atomicAdd(&lh[DST[i] >> shift], 1);
    __syncthreads();
    for (int c = threadIdx.x; c < nbkt; c += blockDim.x)
        hist[(size_t)c * NHB + b] = lh[c];
}

// exclusive scan of each bucket's 1024 per-block counts; total -> bktCnt[c]
__global__ void __launch_bounds__(256) k_scanA(
    int* __restrict__ hist, int* __restrict__ bktCnt)
{
    int c = blockIdx.x;
    int* row = hist + (size_t)c * NHB;
    __shared__ int part[256];
    int t = threadIdx.x;
    int v[4];
    int sum = 0;
    #pragma unroll
    for (int u = 0; u < 4; ++u) { v[u] = row[t * 4 + u]; sum += v[u]; }
    part[t] = sum;
    __syncthreads();
    for (int off = 1; off < 256; off <<= 1) {
        int x = 0;
        if (t >= off) x = part[t - off];
        __syncthreads();
        part[t] += x;
        __syncthreads();
    }
    int run = (t == 0) ? 0 : part[t - 1];
    if (t == 255) bktCnt[c] = part[255];
    #pragma unroll
    for (int u = 0; u < 4; ++u) { int x = v[u]; row[t * 4 + u] = run; run += x; }
}

// exclusive scan of bucket totals -> base[c]; base[nbkt] = e
__global__ void __launch_bounds__(256) k_scanB(
    const int* __restrict__ bktCnt, int* __restrict__ base, int nbkt, int e)
{
    __shared__ int part[256];
    int t = threadIdx.x;
    int v[4];
    int sum = 0;
    #pragma unroll
    for (int u = 0; u < 4; ++u) {
        int idx = t * 4 + u;
        v[u] = (idx < nbkt) ? bktCnt[idx] : 0;
        sum += v[u];
    }
    part[t] = sum;
    __syncthreads();
    for (int off = 1; off < 256; off <<= 1) {
        int x = 0;
        if (t >= off) x = part[t - off];
        __syncthreads();
        part[t] += x;
        __syncthreads();
    }
    int run = (t == 0) ? 0 : part[t - 1];
    #pragma unroll
    for (int u = 0; u < 4; ++u) {
        int idx = t * 4 + u;
        if (idx < nbkt) base[idx] = run;
        run += v[u];
    }
    if (t == 0) base[nbkt] = e;
}

__global__ void __launch_bounds__(256) k_scatter(
    const int* __restrict__ DST, const int* __restrict__ SRC,
    const float* __restrict__ DIST, const float* __restrict__ EF,
    const int* __restrict__ hist, const int* __restrict__ base,
    int* __restrict__ sd_s, float* __restrict__ de_s, float* __restrict__ ef_s,
    int e, int nbkt, int shift, int epb)
{
    __shared__ int loff[1024];
    int b = blockIdx.x;
    for (int c = threadIdx.x; c < nbkt; c += blockDim.x)
        loff[c] = base[c] + hist[(size_t)c * NHB + b];
    __syncthreads();
    int i0 = b * epb, i1 = min(i0 + epb, e);
    int mask = (1 << shift) - 1;
    for (int i = i0 + threadIdx.x; i < i1; i += blockDim.x) {
        int d = DST[i];
        int c = d >> shift;
        int pos = atomicAdd(&loff[c], 1);   // LDS atomic (rank within bucket)
        sd_s[pos] = (SRC[i] << shift) | (d & mask);
        de_s[pos] = DIST[i];
        ef_s[pos] = EF[i];
    }
}

// ============================ node encoder =================================

__global__ void __launch_bounds__(256) k_enc(
    const float* __restrict__ X, const float* __restrict__ W1,
    const float* __restrict__ B1, const float* __restrict__ W2,
    const float* __restrict__ B2, float* __restrict__ H0, int n)
{
    __shared__ float4 w1s[2048];
    for (int t = threadIdx.x; t < 2048; t += blockDim.x)
        w1s[t] = reinterpret_cast<const float4*>(W1)[t];
    __syncthreads();

    int i = blockIdx.x * blockDim.x + threadIdx.x;
    if (i >= n) return;

    const float4* xp = reinterpret_cast<const float4*>(X) + (size_t)i * 32;

    float acc[64];
    #pragma unroll
    for (int j = 0; j < 64; ++j) acc[j] = B1[j];

    for (int k4 = 0; k4 < 32; ++k4) {
        float4 xv = xp[k4];
        #pragma unroll
        for (int kk = 0; kk < 4; ++kk) {
            float x = (&xv.x)[kk];
            const float4* wrow = &w1s[(k4 * 4 + kk) * 16];
            #pragma unroll
            for (int j4 = 0; j4 < 16; ++j4) {
                float4 w = wrow[j4];
                acc[j4*4+0] = fmaf(x, w.x, acc[j4*4+0]);
                acc[j4*4+1] = fmaf(x, w.y, acc[j4*4+1]);
                acc[j4*4+2] = fmaf(x, w.z, acc[j4*4+2]);
                acc[j4*4+3] = fmaf(x, w.w, acc[j4*4+3]);
            }
        }
    }
    float o = B2[0];
    #pragma unroll
    for (int j = 0; j < 64; ++j)
        o = fmaf(fmaxf(acc[j], 0.f), W2[j], o);
    H0[i] = fmaxf(o, 0.f);
}

// ==================== bucketed edge passes (LDS accum) =====================

__global__ void __launch_bounds__(256) k_passA(
    const int* __restrict__ sd_s, const float* __restrict__ de_s,
    const float* __restrict__ H0, const int* __restrict__ base,
    float* __restrict__ H1, int shift, int n)
{
    __shared__ float lsum[1024], lnum[1024];
    int c = blockIdx.x;
    int bw = 1 << shift, mask = bw - 1;
    for (int t = threadIdx.x; t < bw; t += blockDim.x) { lsum[t] = 0.f; lnum[t] = 0.f; }
    __syncthreads();
    int i0 = base[c], i1 = base[c + 1];
    for (int i = i0 + threadIdx.x; i < i1; i += blockDim.x) {
        int sd = sd_s[i];
        float ev = __expf(de_s[i]);
        atomicAdd(&lsum[sd & mask], ev);
        atomicAdd(&lnum[sd & mask], ev * H0[sd >> shift]);
    }
    __syncthreads();
    int d0 = c << shift;
    for (int t = threadIdx.x; t < bw; t += blockDim.x) {
        int d = d0 + t;
        if (d < n) {
            float s = lsum[t];
            H1[d] = (s != 0.f) ? lnum[t] / s : 0.f;
        }
    }
}

__global__ void __launch_bounds__(256) k_passB(
    const int* __restrict__ sd_s, const float* __restrict__ ef_s,
    const float* __restrict__ H1,
    const float* __restrict__ W1, const float* __restrict__ B1,
    const float* __restrict__ W2, const float* __restrict__ B2,
    const int* __restrict__ base,
    float* __restrict__ e2_s, float* __restrict__ AGG, float* __restrict__ S2,
    int shift, int n)
{
    __shared__ float4 wA[16], wB[16], wC[16], wD[16], wV[16];
    __shared__ float h1loc[1024], lagg[1024], ls2[1024];
    int bw = 1 << shift, mask = bw - 1;
    int c = blockIdx.x;
    if (threadIdx.x < 16) {
        int j4 = threadIdx.x;
        const float4* W1v = reinterpret_cast<const float4*>(W1);
        wA[j4] = W1v[j4];
        wB[j4] = W1v[16 + j4];
        wC[j4] = W1v[32 + j4];
        wD[j4] = reinterpret_cast<const float4*>(B1)[j4];
        wV[j4] = reinterpret_cast<const float4*>(W2)[j4];
    }
    int d0 = c << shift;
    for (int t = threadIdx.x; t < bw; t += blockDim.x) {
        int d = d0 + t;
        h1loc[t] = (d < n) ? H1[d] : 0.f;
        lagg[t] = 0.f;
        ls2[t] = 0.f;
    }
    __syncthreads();
    const float b2 = B2[0];
    int i0 = base[c], i1 = base[c + 1];
    const int T = blockDim.x;
    for (int i = i0 + (int)threadIdx.x; i < i1; i += 4 * T) {
        float x0[4], hs[4], hd[4], o[4];
        int lo[4], pos[4];
        bool val[4];
        #pragma unroll
        for (int u = 0; u < 4; ++u) {
            int j = i + u * T;
            val[u] = (j < i1);
            pos[u] = j;
            if (val[u]) {
                int sd = sd_s[j];
                lo[u] = sd & mask;
                x0[u] = ef_s[j];
                hs[u] = H1[sd >> shift];
                hd[u] = h1loc[lo[u]];
            } else { lo[u] = 0; x0[u] = 0.f; hs[u] = 0.f; hd[u] = 0.f; }
            o[u] = b2;
        }
        #pragma unroll
        for (int j4 = 0; j4 < 16; ++j4) {
            float4 a = wA[j4], b = wB[j4], cc = wC[j4], dd = wD[j4], v = wV[j4];
            #pragma unroll
            for (int u = 0; u < 4; ++u) {
                float t0 = fmaf(x0[u], a.x, fmaf(hs[u], b.x, fmaf(hd[u], cc.x, dd.x)));
                o[u] = fmaf(fmaxf(t0, 0.f), v.x, o[u]);
                float t1 = fmaf(x0[u], a.y, fmaf(hs[u], b.y, fmaf(hd[u], cc.y, dd.y)));
                o[u] = fmaf(fmaxf(t1, 0.f), v.y, o[u]);
                float t2 = fmaf(x0[u], a.z, fmaf(hs[u], b.z, fmaf(hd[u], cc.z, dd.z)));
                o[u] = fmaf(fmaxf(t2, 0.f), v.z, o[u]);
                float t3 = fmaf(x0[u], a.w, fmaf(hs[u], b.w, fmaf(hd[u], cc.w, dd.w)));
                o[u] = fmaf(fmaxf(t3, 0.f), v.w, o[u]);
            }
        }
        #pragma unroll
        for (int u = 0; u < 4; ++u) {
            if (val[u]) {
                float eh = fmaxf(o[u], 0.f);
                float ex = __expf(eh);
                e2_s[pos[u]] = ex;
                atomicAdd(&lagg[lo[u]], eh);
                atomicAdd(&ls2[lo[u]], ex);
            }
        }
    }
    __syncthreads();
    for (int t = threadIdx.x; t < bw; t += blockDim.x) {
        int d = d0 + t;
        if (d < n) { AGG[d] = lagg[t]; S2[d] = ls2[t]; }
    }
}

__global__ void __launch_bounds__(256) k_passC(
    const int* __restrict__ sd_s, const float* __restrict__ e2_s,
    const float* __restrict__ H2, const int* __restrict__ base,
    float* __restrict__ NUM2, int shift, int n)
{
    __shared__ float lnum[1024];
    int c = blockIdx.x;
    int bw = 1 << shift, mask = bw - 1;
    for (int t = threadIdx.x; t < bw; t += blockDim.x) lnum[t] = 0.f;
    __syncthreads();
    int i0 = base[c], i1 = base[c + 1];
    for (int i = i0 + threadIdx.x; i < i1; i += blockDim.x) {
        int sd = sd_s[i];
        atomicAdd(&lnum[sd & mask], e2_s[i] * H2[sd >> shift]);
    }
    __syncthreads();
    int d0 = c << shift;
    for (int t = threadIdx.x; t < bw; t += blockDim.x) {
        int d = d0 + t;
        if (d < n) NUM2[d] = lnum[t];
    }
}

// ============================ node MLPs ====================================

__global__ void k_nu(const float* __restrict__ AGG, const float* __restrict__ H1,
                     const float* __restrict__ W1, const float* __restrict__ B1,
                     const float* __restrict__ W2, const float* __restrict__ B2,
                     float* __restrict__ H2, int n)
{
    int i = blockIdx.x * blockDim.x + threadIdx.x;
    if (i >= n) return;
    float x0 = AGG[i], x1 = H1[i];
    float o = B2[0];
    #pragma unroll
    for (int j = 0; j < 64; ++j) {
        float a = fmaf(x0, W1[j], fmaf(x1, W1[64 + j], B1[j]));
        o = fmaf(fmaxf(a, 0.f), W2[j], o);
    }
    H2[i] = fmaxf(o, 0.f);
}

__global__ void k_final(const float* __restrict__ NUM2, const float* __restrict__ S2,
                        const float* __restrict__ W1, const float* __restrict__ B1,
                        const float* __restrict__ W2, const float* __restrict__ B2,
                        float* __restrict__ OUT, int n)
{
    int i = blockIdx.x * blockDim.x + threadIdx.x;
    if (i >= n) return;
    float s = S2[i];
    float x = (s != 0.f) ? NUM2[i] / s : 0.f;
    float o = B2[0];
    #pragma unroll
    for (int j = 0; j < 64; ++j) {
        float a = fmaf(x, W1[j], B1[j]);
        o = fmaf(fmaxf(a, 0.f), W2[j], o);
    }
    OUT[i] = fmaxf(o, 0.f);
}

// ===================== fallback (round-1 atomic path) ======================

__device__ __forceinline__ void atomAddF(float* p, float v) { unsafeAtomicAdd(p, v); }

__global__ void k_zero(float* __restrict__ p, int n) {
    int i = blockIdx.x * blockDim.x + threadIdx.x;
    if (i < n) p[i] = 0.f;
}

__global__ void __launch_bounds__(256) k_agg1(
    const float* __restrict__ DIST, const int* __restrict__ SRC,
    const int* __restrict__ DST, const float* __restrict__ H0,
    float* __restrict__ S1, float* __restrict__ NUM1, int e)
{
    int i = blockIdx.x * blockDim.x + threadIdx.x;
    if (i >= e) return;
    float ev = __expf(DIST[i]);
    atomAddF(&S1[DST[i]], ev);
    atomAddF(&NUM1[DST[i]], ev * H0[SRC[i]]);
}

__global__ void k_div(const float* __restrict__ NUM, const float* __restrict__ S,
                      float* __restrict__ H, int n) {
    int i = blockIdx.x * blockDim.x + threadIdx.x;
    if (i < n) {
        float s = S[i];
        H[i] = (s != 0.f) ? NUM[i] / s : 0.f;
    }
}

__global__ void __launch_bounds__(256) k_edgeF(
    const float* __restrict__ EF, const int* __restrict__ SRC,
    const int* __restrict__ DST, const float* __restrict__ H1,
    const float* __restrict__ W1, const float* __restrict__ B1,
    const float* __restrict__ W2, const float* __restrict__ B2,
    float* __restrict__ E2, float* __restrict__ AGG, float* __restrict__ S2, int e)
{
    int i = blockIdx.x * blockDim.x + threadIdx.x;
    if (i >= e) return;
    float x0 = EF[i];
    int s = SRC[i], d = DST[i];
    float h_s = H1[s], h_d = H1[d];
    float o = B2[0];
    for (int j = 0; j < 64; ++j) {
        float aj = fmaf(x0, W1[j], fmaf(h_s, W1[64+j], fmaf(h_d, W1[128+j], B1[j])));
        o = fmaf(fmaxf(aj, 0.f), W2[j], o);
    }
    float eh = fmaxf(o, 0.f);
    float ex = __expf(eh);
    E2[i] = ex;
    atomAddF(&AGG[d], eh);
    atomAddF(&S2[d], ex);
}

__global__ void __launch_bounds__(256) k_agg2F(
    const float* __restrict__ E2, const int* __restrict__ SRC,
    const int* __restrict__ DST, const float* __restrict__ H2,
    float* __restrict__ NUM2, int e)
{
    int i = blockIdx.x * blockDim.x + threadIdx.x;
    if (i >= e) return;
    atomAddF(&NUM2[DST[i]], E2[i] * H2[SRC[i]]);
}

// ============================ launch =======================================

extern "C" void kernel_launch(void* const* d_in, const int* in_sizes, int n_in,
                              void* d_out, int out_size, void* d_ws, size_t ws_size,
                              hipStream_t stream)
{
    const float* node_feat = (const float*)d_in[0];
    const float* edge_feat = (const float*)d_in[1];
    const float* edge_dist = (const float*)d_in[2];
    const int*   src       = (const int*)d_in[3];
    const int*   dst       = (const int*)d_in[4];
    const float* enc_w1 = (const float*)d_in[5];
    const float* enc_b1 = (const float*)d_in[6];
    const float* enc_w2 = (const float*)d_in[7];
    const float* enc_b2 = (const float*)d_in[8];
    const float* nu_w1  = (const float*)d_in[9];
    const float* nu_b1  = (const float*)d_in[10];
    const float* nu_w2  = (const float*)d_in[11];
    const float* nu_b2  = (const float*)d_in[12];
    const float* eu_w1  = (const float*)d_in[13];
    const float* eu_b1  = (const float*)d_in[14];
    const float* eu_w2  = (const float*)d_in[15];
    const float* eu_b2  = (const float*)d_in[16];
    const float* dec_w1 = (const float*)d_in[17];
    const float* dec_b1 = (const float*)d_in[18];
    const float* dec_w2 = (const float*)d_in[19];
    const float* dec_b2 = (const float*)d_in[20];

    const int n = in_sizes[0] / 128;
    const int e = in_sizes[1];
    const int B = 256;

    // coarse bucket shift: buckets <= 1024 and width <= 1024
    int shift = 7;
    while ((((n + (1 << shift) - 1) >> shift) > 1024) && shift < 10) shift++;
    const int nbkt = (n + (1 << shift) - 1) >> shift;
    const int epb  = (e + NHB - 1) / NHB;

    // ws layout (4B units):
    // h0,h1,agg,s2,h2,num2 [6n] | base[nbkt+1] bktCnt[nbkt] hist[nbkt*NHB] |
    // sd_s[e] de_s[e](=e2_s) ef_s[e]
    size_t need = ((size_t)6 * n + (size_t)2 * nbkt + 1 +
                   (size_t)nbkt * NHB + (size_t)3 * e) * 4;

    float* ws   = (float*)d_ws;
    float* h0   = ws;
    float* h1   = ws + (size_t)1 * n;
    float* agg  = ws + (size_t)2 * n;
    float* s2   = ws + (size_t)3 * n;
    float* h2   = ws + (size_t)4 * n;
    float* num2 = ws + (size_t)5 * n;

    if (ws_size >= need && nbkt <= 1024 && (1 << shift) <= 1024) {
        int*   base  = (int*)(ws + (size_t)6 * n);
        int*   bktCnt= base + nbkt + 1;
        int*   hist  = bktCnt + nbkt;
        int*   sd_s  = hist + (size_t)nbkt * NHB;
        float* de_s  = (float*)(sd_s + e);   // dist sorted; reused as e2 later
        float* ef_s  = de_s + e;

        hipLaunchKernelGGL(k_chist, dim3(NHB), dim3(B), 0, stream,
                           dst, hist, e, nbkt, shift, epb);
        hipLaunchKernelGGL(k_scanA, dim3(nbkt), dim3(B), 0, stream, hist, bktCnt);
        hipLaunchKernelGGL(k_scanB, dim3(1), dim3(B), 0, stream, bktCnt, base, nbkt, e);
        hipLaunchKernelGGL(k_scatter, dim3(NHB), dim3(B), 0, stream,
                           dst, src, edge_dist, edge_feat, hist, base,
                           sd_s, de_s, ef_s, e, nbkt, shift, epb);
        hipLaunchKernelGGL(k_enc, dim3((n + B - 1) / B), dim3(B), 0, stream,
                           node_feat, enc_w1, enc_b1, enc_w2, enc_b2, h0, n);
        hipLaunchKernelGGL(k_passA, dim3(nbkt), dim3(B), 0, stream,
                           sd_s, de_s, h0, base, h1, shift, n);
        hipLaunchKernelGGL(k_passB, dim3(nbkt), dim3(B), 0, stream,
                           sd_s, ef_s, h1, eu_w1, eu_b1, eu_w2, eu_b2, base,
                           de_s /*e2_s*/, agg, s2, shift, n);
        hipLaunchKernelGGL(k_nu, dim3((n + B - 1) / B), dim3(B), 0, stream,
                           agg, h1, nu_w1, nu_b1, nu_w2, nu_b2, h2, n);
        hipLaunchKernelGGL(k_passC, dim3(nbkt), dim3(B), 0, stream,
                           sd_s, de_s /*e2_s*/, h2, base, num2, shift, n);
        hipLaunchKernelGGL(k_final, dim3((n + B - 1) / B), dim3(B), 0, stream,
                           num2, s2, dec_w1, dec_b1, dec_w2, dec_b2, (float*)d_out, n);
    } else {
        // fallback: round-1 atomic path (needs 8n + e floats)
        float* s1   = ws + (size_t)6 * n;
        float* num1 = ws + (size_t)7 * n;
        float* e2   = ws + (size_t)8 * n;
        hipLaunchKernelGGL(k_zero, dim3((6 * n + B - 1) / B), dim3(B), 0, stream,
                           agg, 6 * n);  // zeros agg,s2,h2,num2,s1,num1
        hipLaunchKernelGGL(k_enc, dim3((n + B - 1) / B), dim3(B), 0, stream,
                           node_feat, enc_w1, enc_b1, enc_w2, enc_b2, h0, n);
        hipLaunchKernelGGL(k_agg1, dim3((e + B - 1) / B), dim3(B), 0, stream,
                           edge_dist, src, dst, h0, s1, num1, e);
        hipLaunchKernelGGL(k_div, dim3((n + B - 1) / B), dim3(B), 0, stream,
                           num1, s1, h1, n);
        hipLaunchKernelGGL(k_edgeF, dim3((e + B - 1) / B), dim3(B), 0, stream,
                           edge_feat, src, dst, h1, eu_w1, eu_b1, eu_w2, eu_b2,
                           e2, agg, s2, e);
        hipLaunchKernelGGL(k_nu, dim3((n + B - 1) / B), dim3(B), 0, stream,
                           agg, h1, nu_w1, nu_b1, nu_w2, nu_b2, h2, n);
        hipLaunchKernelGGL(k_agg2F, dim3((e + B - 1) / B), dim3(B), 0, stream,
                           e2, src, dst, h2, num2, e);
        hipLaunchKernelGGL(k_final, dim3((n + B - 1) / B), dim3(B), 0, stream,
                           num2, s2, dec_w1, dec_b1, dec_w2, dec_b2, (float*)d_out, n);
    }
}

// Round 3
// 482.159 us; speedup vs baseline: 3.4413x; 1.2699x over previous
//
#include <hip/hip_runtime.h>

// ---------------------------------------------------------------------------
// GraphElementNetwork forward, bucketed (atomic-free) path, v3:
//  - bucket by dst>>8 (width 256, nbkt=391) -> pass grids still > 256 CUs
//  - scatter writes ONE float2 (sd,dist) + ONE float (ef) per edge,
//    NHB=256 blocks: open-line set ~100KB/block, 3.2MB/XCD < 4MB L2
//    (round-2: 3 arrays x 782 buckets x 1024 blocks = 38MB/XCD -> 7x write amp)
//  - k_div folded into passA, k_nu into passB, k_final into passC
// ---------------------------------------------------------------------------

#define NHB 256   // histogram / scatter blocks (1 per CU)

// ============================ bucketing ====================================

__global__ void __launch_bounds__(256) k_chist(
    const int* __restrict__ DST, int* __restrict__ hist,
    int e, int nbkt, int shift, int epb)
{
    __shared__ int lh[512];
    for (int c = threadIdx.x; c < nbkt; c += blockDim.x) lh[c] = 0;
    __syncthreads();
    int b = blockIdx.x;
    int i0 = b * epb, i1 = min(i0 + epb, e);
    int nq = (i1 > i0) ? ((i1 - i0) >> 2) : 0;
    const int4* D4 = reinterpret_cast<const int4*>(DST + i0);
    for (int q = threadIdx.x; q < nq; q += blockDim.x) {
        int4 d = D4[q];
        atomicAdd(&lh[d.x >> shift], 1);
        atomicAdd(&lh[d.y >> shift], 1);
        atomicAdd(&lh[d.z >> shift], 1);
        atomicAdd(&lh[d.w >> shift], 1);
    }
    // tail
    for (int i = i0 + 4 * nq + threadIdx.x; i < i1; i += blockDim.x)
        atomicAdd(&lh[DST[i] >> shift], 1);
    __syncthreads();
    for (int c = threadIdx.x; c < nbkt; c += blockDim.x)
        hist[(size_t)c * NHB + b] = lh[c];
}

// exclusive scan of each bucket's NHB per-block counts; total -> bktCnt[c]
__global__ void __launch_bounds__(256) k_scanA(
    int* __restrict__ hist, int* __restrict__ bktCnt)
{
    int c = blockIdx.x;
    int* row = hist + (size_t)c * NHB;
    __shared__ int part[256];
    int t = threadIdx.x;
    int v = row[t];
    part[t] = v;
    __syncthreads();
    for (int off = 1; off < 256; off <<= 1) {
        int x = 0;
        if (t >= off) x = part[t - off];
        __syncthreads();
        part[t] += x;
        __syncthreads();
    }
    if (t == 255) bktCnt[c] = part[255];
    row[t] = part[t] - v;   // exclusive
}

// exclusive scan of bucket totals -> base[c]; base[nbkt] = e
__global__ void __launch_bounds__(256) k_scanB(
    const int* __restrict__ bktCnt, int* __restrict__ base, int nbkt, int e)
{
    __shared__ int part[256];
    int t = threadIdx.x;
    int v[4];
    int sum = 0;
    #pragma unroll
    for (int u = 0; u < 4; ++u) {
        int idx = t * 4 + u;
        v[u] = (idx < nbkt) ? bktCnt[idx] : 0;
        sum += v[u];
    }
    part[t] = sum;
    __syncthreads();
    for (int off = 1; off < 256; off <<= 1) {
        int x = 0;
        if (t >= off) x = part[t - off];
        __syncthreads();
        part[t] += x;
        __syncthreads();
    }
    int run = (t == 0) ? 0 : part[t - 1];
    #pragma unroll
    for (int u = 0; u < 4; ++u) {
        int idx = t * 4 + u;
        if (idx < nbkt) base[idx] = run;
        run += v[u];
    }
    if (t == 0) base[nbkt] = e;
}

__global__ void __launch_bounds__(256) k_scatter(
    const int* __restrict__ DST, const int* __restrict__ SRC,
    const float* __restrict__ DIST, const float* __restrict__ EF,
    const int* __restrict__ hist, const int* __restrict__ base,
    float2* __restrict__ payA, float* __restrict__ ef_s,
    int e, int nbkt, int shift, int epb)
{
    __shared__ int loff[512];
    int b = blockIdx.x;
    for (int c = threadIdx.x; c < nbkt; c += blockDim.x)
        loff[c] = base[c] + hist[(size_t)c * NHB + b];
    __syncthreads();
    int i0 = b * epb, i1 = min(i0 + epb, e);
    if (i0 >= i1) return;
    int mask = (1 << shift) - 1;
    int nq = (i1 - i0) >> 2;
    const int4*   D4 = reinterpret_cast<const int4*>(DST + i0);
    const int4*   S4 = reinterpret_cast<const int4*>(SRC + i0);
    const float4* T4 = reinterpret_cast<const float4*>(DIST + i0);
    const float4* F4 = reinterpret_cast<const float4*>(EF + i0);
    for (int q = threadIdx.x; q < nq; q += blockDim.x) {
        int4 dv = D4[q];
        int4 sv = S4[q];
        float4 tv = T4[q];
        float4 fv = F4[q];
        #pragma unroll
        for (int u = 0; u < 4; ++u) {
            int d = (&dv.x)[u];
            int c = d >> shift;
            int pos = atomicAdd(&loff[c], 1);   // LDS atomic rank
            int sd = ((&sv.x)[u] << shift) | (d & mask);
            payA[pos] = make_float2(__int_as_float(sd), (&tv.x)[u]);
            ef_s[pos] = (&fv.x)[u];
        }
    }
    for (int i = i0 + 4 * nq + threadIdx.x; i < i1; i += blockDim.x) {
        int d = DST[i];
        int c = d >> shift;
        int pos = atomicAdd(&loff[c], 1);
        int sd = (SRC[i] << shift) | (d & mask);
        payA[pos] = make_float2(__int_as_float(sd), DIST[i]);
        ef_s[pos] = EF[i];
    }
}

// ============================ node encoder =================================

__global__ void __launch_bounds__(256) k_enc(
    const float* __restrict__ X, const float* __restrict__ W1,
    const float* __restrict__ B1, const float* __restrict__ W2,
    const float* __restrict__ B2, float* __restrict__ H0, int n)
{
    __shared__ float4 w1s[2048];
    for (int t = threadIdx.x; t < 2048; t += blockDim.x)
        w1s[t] = reinterpret_cast<const float4*>(W1)[t];
    __syncthreads();

    int i = blockIdx.x * blockDim.x + threadIdx.x;
    if (i >= n) return;

    const float4* xp = reinterpret_cast<const float4*>(X) + (size_t)i * 32;

    float acc[64];
    #pragma unroll
    for (int j = 0; j < 64; ++j) acc[j] = B1[j];

    for (int k4 = 0; k4 < 32; ++k4) {
        float4 xv = xp[k4];
        #pragma unroll
        for (int kk = 0; kk < 4; ++kk) {
            float x = (&xv.x)[kk];
            const float4* wrow = &w1s[(k4 * 4 + kk) * 16];
            #pragma unroll
            for (int j4 = 0; j4 < 16; ++j4) {
                float4 w = wrow[j4];
                acc[j4*4+0] = fmaf(x, w.x, acc[j4*4+0]);
                acc[j4*4+1] = fmaf(x, w.y, acc[j4*4+1]);
                acc[j4*4+2] = fmaf(x, w.z, acc[j4*4+2]);
                acc[j4*4+3] = fmaf(x, w.w, acc[j4*4+3]);
            }
        }
    }
    float o = B2[0];
    #pragma unroll
    for (int j = 0; j < 64; ++j)
        o = fmaf(fmaxf(acc[j], 0.f), W2[j], o);
    H0[i] = fmaxf(o, 0.f);
}

// ==================== bucketed edge passes (LDS accum) =====================

// passA: softmax-agg #1 -> H1 (k_div folded in)
__global__ void __launch_bounds__(256) k_passA(
    const float2* __restrict__ payA, const float* __restrict__ H0,
    const int* __restrict__ base, float* __restrict__ H1, int shift, int n)
{
    __shared__ float lsum[1024], lnum[1024];
    int c = blockIdx.x;
    int bw = 1 << shift, mask = bw - 1;
    for (int t = threadIdx.x; t < bw; t += blockDim.x) { lsum[t] = 0.f; lnum[t] = 0.f; }
    __syncthreads();
    int i0 = base[c], i1 = base[c + 1];
    for (int i = i0 + threadIdx.x; i < i1; i += blockDim.x) {
        float2 pa = payA[i];
        int sd = __float_as_int(pa.x);
        float ev = __expf(pa.y);
        atomicAdd(&lsum[sd & mask], ev);
        atomicAdd(&lnum[sd & mask], ev * H0[sd >> shift]);
    }
    __syncthreads();
    int d0 = c << shift;
    for (int t = threadIdx.x; t < bw; t += blockDim.x) {
        int d = d0 + t;
        if (d < n) {
            float s = lsum[t];
            H1[d] = (s != 0.f) ? lnum[t] / s : 0.f;
        }
    }
}

// passB: edge MLP -> e2 (overwrites ef_s), agg/s2 bins; k_nu folded -> H2, S2
__global__ void __launch_bounds__(256) k_passB(
    const float2* __restrict__ payA, float* __restrict__ ef_s,
    const float* __restrict__ H1,
    const float* __restrict__ W1, const float* __restrict__ B1,
    const float* __restrict__ W2, const float* __restrict__ B2,
    const float* __restrict__ NW1, const float* __restrict__ NB1,
    const float* __restrict__ NW2, const float* __restrict__ NB2,
    const int* __restrict__ base,
    float* __restrict__ H2, float* __restrict__ S2,
    int shift, int n)
{
    __shared__ float4 wA[16], wB[16], wC[16], wD[16], wV[16];
    __shared__ float h1loc[1024], lagg[1024], ls2[1024];
    int bw = 1 << shift, mask = bw - 1;
    int c = blockIdx.x;
    if (threadIdx.x < 16) {
        int j4 = threadIdx.x;
        const float4* W1v = reinterpret_cast<const float4*>(W1);
        wA[j4] = W1v[j4];
        wB[j4] = W1v[16 + j4];
        wC[j4] = W1v[32 + j4];
        wD[j4] = reinterpret_cast<const float4*>(B1)[j4];
        wV[j4] = reinterpret_cast<const float4*>(W2)[j4];
    }
    int d0 = c << shift;
    for (int t = threadIdx.x; t < bw; t += blockDim.x) {
        int d = d0 + t;
        h1loc[t] = (d < n) ? H1[d] : 0.f;
        lagg[t] = 0.f;
        ls2[t] = 0.f;
    }
    __syncthreads();
    const float b2 = B2[0];
    int i0 = base[c], i1 = base[c + 1];
    const int T = blockDim.x;
    for (int i = i0 + (int)threadIdx.x; i < i1; i += 4 * T) {
        float x0[4], hs[4], hd[4], o[4];
        int lo[4], pos[4];
        bool val[4];
        #pragma unroll
        for (int u = 0; u < 4; ++u) {
            int j = i + u * T;
            val[u] = (j < i1);
            pos[u] = j;
            if (val[u]) {
                float2 pa = payA[j];
                int sd = __float_as_int(pa.x);
                lo[u] = sd & mask;
                x0[u] = ef_s[j];
                hs[u] = H1[sd >> shift];
                hd[u] = h1loc[lo[u]];
            } else { lo[u] = 0; x0[u] = 0.f; hs[u] = 0.f; hd[u] = 0.f; }
            o[u] = b2;
        }
        #pragma unroll
        for (int j4 = 0; j4 < 16; ++j4) {
            float4 a = wA[j4], b = wB[j4], cc = wC[j4], dd = wD[j4], v = wV[j4];
            #pragma unroll
            for (int u = 0; u < 4; ++u) {
                float t0 = fmaf(x0[u], a.x, fmaf(hs[u], b.x, fmaf(hd[u], cc.x, dd.x)));
                o[u] = fmaf(fmaxf(t0, 0.f), v.x, o[u]);
                float t1 = fmaf(x0[u], a.y, fmaf(hs[u], b.y, fmaf(hd[u], cc.y, dd.y)));
                o[u] = fmaf(fmaxf(t1, 0.f), v.y, o[u]);
                float t2 = fmaf(x0[u], a.z, fmaf(hs[u], b.z, fmaf(hd[u], cc.z, dd.z)));
                o[u] = fmaf(fmaxf(t2, 0.f), v.z, o[u]);
                float t3 = fmaf(x0[u], a.w, fmaf(hs[u], b.w, fmaf(hd[u], cc.w, dd.w)));
                o[u] = fmaf(fmaxf(t3, 0.f), v.w, o[u]);
            }
        }
        #pragma unroll
        for (int u = 0; u < 4; ++u) {
            if (val[u]) {
                float eh = fmaxf(o[u], 0.f);
                float ex = __expf(eh);
                ef_s[pos[u]] = ex;          // e2 overwrites consumed ef
                atomicAdd(&lagg[lo[u]], eh);
                atomicAdd(&ls2[lo[u]], ex);
            }
        }
    }
    __syncthreads();
    // k_nu folded: H2 = nuMLP(agg, h1), plus S2 writeout
    for (int t = threadIdx.x; t < bw; t += blockDim.x) {
        int d = d0 + t;
        if (d < n) {
            float xa = lagg[t], xh = h1loc[t];
            float o = NB2[0];
            #pragma unroll
            for (int j = 0; j < 64; ++j) {
                float a = fmaf(xa, NW1[j], fmaf(xh, NW1[64 + j], NB1[j]));
                o = fmaf(fmaxf(a, 0.f), NW2[j], o);
            }
            H2[d] = fmaxf(o, 0.f);
            S2[d] = ls2[t];
        }
    }
}

// passC: softmax-agg #2 numerator + decoder (k_final folded) -> OUT
__global__ void __launch_bounds__(256) k_passC(
    const float2* __restrict__ payA, const float* __restrict__ e2_s,
    const float* __restrict__ H2, const float* __restrict__ S2,
    const float* __restrict__ W1, const float* __restrict__ B1,
    const float* __restrict__ W2, const float* __restrict__ B2,
    const int* __restrict__ base, float* __restrict__ OUT, int shift, int n)
{
    __shared__ float lnum[1024];
    int c = blockIdx.x;
    int bw = 1 << shift, mask = bw - 1;
    for (int t = threadIdx.x; t < bw; t += blockDim.x) lnum[t] = 0.f;
    __syncthreads();
    int i0 = base[c], i1 = base[c + 1];
    for (int i = i0 + threadIdx.x; i < i1; i += blockDim.x) {
        float2 pa = payA[i];
        int sd = __float_as_int(pa.x);
        atomicAdd(&lnum[sd & mask], e2_s[i] * H2[sd >> shift]);
    }
    __syncthreads();
    int d0 = c << shift;
    for (int t = threadIdx.x; t < bw; t += blockDim.x) {
        int d = d0 + t;
        if (d < n) {
            float s = S2[d];
            float x = (s != 0.f) ? lnum[t] / s : 0.f;
            float o = B2[0];
            #pragma unroll
            for (int j = 0; j < 64; ++j) {
                float a = fmaf(x, W1[j], B1[j]);
                o = fmaf(fmaxf(a, 0.f), W2[j], o);
            }
            OUT[d] = fmaxf(o, 0.f);
        }
    }
}

// ===================== fallback (round-1 atomic path) ======================

__device__ __forceinline__ void atomAddF(float* p, float v) { unsafeAtomicAdd(p, v); }

__global__ void k_zero(float* __restrict__ p, int n) {
    int i = blockIdx.x * blockDim.x + threadIdx.x;
    if (i < n) p[i] = 0.f;
}

__global__ void __launch_bounds__(256) k_agg1(
    const float* __restrict__ DIST, const int* __restrict__ SRC,
    const int* __restrict__ DST, const float* __restrict__ H0,
    float* __restrict__ S1, float* __restrict__ NUM1, int e)
{
    int i = blockIdx.x * blockDim.x + threadIdx.x;
    if (i >= e) return;
    float ev = __expf(DIST[i]);
    atomAddF(&S1[DST[i]], ev);
    atomAddF(&NUM1[DST[i]], ev * H0[SRC[i]]);
}

__global__ void k_div(const float* __restrict__ NUM, const float* __restrict__ S,
                      float* __restrict__ H, int n) {
    int i = blockIdx.x * blockDim.x + threadIdx.x;
    if (i < n) {
        float s = S[i];
        H[i] = (s != 0.f) ? NUM[i] / s : 0.f;
    }
}

__global__ void __launch_bounds__(256) k_edgeF(
    const float* __restrict__ EF, const int* __restrict__ SRC,
    const int* __restrict__ DST, const float* __restrict__ H1,
    const float* __restrict__ W1, const float* __restrict__ B1,
    const float* __restrict__ W2, const float* __restrict__ B2,
    float* __restrict__ E2, float* __restrict__ AGG, float* __restrict__ S2, int e)
{
    int i = blockIdx.x * blockDim.x + threadIdx.x;
    if (i >= e) return;
    float x0 = EF[i];
    int s = SRC[i], d = DST[i];
    float h_s = H1[s], h_d = H1[d];
    float o = B2[0];
    for (int j = 0; j < 64; ++j) {
        float aj = fmaf(x0, W1[j], fmaf(h_s, W1[64+j], fmaf(h_d, W1[128+j], B1[j])));
        o = fmaf(fmaxf(aj, 0.f), W2[j], o);
    }
    float eh = fmaxf(o, 0.f);
    float ex = __expf(eh);
    E2[i] = ex;
    atomAddF(&AGG[d], eh);
    atomAddF(&S2[d], ex);
}

__global__ void k_nu(const float* __restrict__ AGG, const float* __restrict__ H1,
                     const float* __restrict__ W1, const float* __restrict__ B1,
                     const float* __restrict__ W2, const float* __restrict__ B2,
                     float* __restrict__ H2, int n)
{
    int i = blockIdx.x * blockDim.x + threadIdx.x;
    if (i >= n) return;
    float x0 = AGG[i], x1 = H1[i];
    float o = B2[0];
    #pragma unroll
    for (int j = 0; j < 64; ++j) {
        float a = fmaf(x0, W1[j], fmaf(x1, W1[64 + j], B1[j]));
        o = fmaf(fmaxf(a, 0.f), W2[j], o);
    }
    H2[i] = fmaxf(o, 0.f);
}

__global__ void __launch_bounds__(256) k_agg2F(
    const float* __restrict__ E2, const int* __restrict__ SRC,
    const int* __restrict__ DST, const float* __restrict__ H2,
    float* __restrict__ NUM2, int e)
{
    int i = blockIdx.x * blockDim.x + threadIdx.x;
    if (i >= e) return;
    atomAddF(&NUM2[DST[i]], E2[i] * H2[SRC[i]]);
}

__global__ void k_final(const float* __restrict__ NUM2, const float* __restrict__ S2,
                        const float* __restrict__ W1, const float* __restrict__ B1,
                        const float* __restrict__ W2, const float* __restrict__ B2,
                        float* __restrict__ OUT, int n)
{
    int i = blockIdx.x * blockDim.x + threadIdx.x;
    if (i >= n) return;
    float s = S2[i];
    float x = (s != 0.f) ? NUM2[i] / s : 0.f;
    float o = B2[0];
    #pragma unroll
    for (int j = 0; j < 64; ++j) {
        float a = fmaf(x, W1[j], B1[j]);
        o = fmaf(fmaxf(a, 0.f), W2[j], o);
    }
    OUT[i] = fmaxf(o, 0.f);
}

// ============================ launch =======================================

extern "C" void kernel_launch(void* const* d_in, const int* in_sizes, int n_in,
                              void* d_out, int out_size, void* d_ws, size_t ws_size,
                              hipStream_t stream)
{
    const float* node_feat = (const float*)d_in[0];
    const float* edge_feat = (const float*)d_in[1];
    const float* edge_dist = (const float*)d_in[2];
    const int*   src       = (const int*)d_in[3];
    const int*   dst       = (const int*)d_in[4];
    const float* enc_w1 = (const float*)d_in[5];
    const float* enc_b1 = (const float*)d_in[6];
    const float* enc_w2 = (const float*)d_in[7];
    const float* enc_b2 = (const float*)d_in[8];
    const float* nu_w1  = (const float*)d_in[9];
    const float* nu_b1  = (const float*)d_in[10];
    const float* nu_w2  = (const float*)d_in[11];
    const float* nu_b2  = (const float*)d_in[12];
    const float* eu_w1  = (const float*)d_in[13];
    const float* eu_b1  = (const float*)d_in[14];
    const float* eu_w2  = (const float*)d_in[15];
    const float* eu_b2  = (const float*)d_in[16];
    const float* dec_w1 = (const float*)d_in[17];
    const float* dec_b1 = (const float*)d_in[18];
    const float* dec_w2 = (const float*)d_in[19];
    const float* dec_b2 = (const float*)d_in[20];

    const int n = in_sizes[0] / 128;
    const int e = in_sizes[1];
    const int B = 256;

    // bucket shift: buckets <= 512, width <= 1024
    int shift = 8;
    while ((((n + (1 << shift) - 1) >> shift) > 512) && shift < 10) shift++;
    const int nbkt = (n + (1 << shift) - 1) >> shift;
    int epb = (e + NHB - 1) / NHB;
    epb = (epb + 3) & ~3;   // keep 16B alignment of per-block ranges

    // ws layout (4B words): h0,h1,h2,s2 [4n] | base[nbkt+1] bktCnt[nbkt]
    // hist[nbkt*NHB] | (pad to 8B) payA[2e] | ef_s[e]
    float* ws = (float*)d_ws;
    size_t w = (size_t)4 * n;
    int* base   = (int*)(ws + w); w += nbkt + 1;
    int* bktCnt = (int*)(ws + w); w += nbkt;
    int* hist   = (int*)(ws + w); w += (size_t)nbkt * NHB;
    w = (w + 1) & ~(size_t)1;
    float2* payA = (float2*)(ws + w); w += (size_t)2 * e;
    float* ef_s  = ws + w; w += e;
    size_t need = w * 4;

    float* h0 = ws;
    float* h1 = ws + (size_t)1 * n;
    float* h2 = ws + (size_t)2 * n;
    float* s2 = ws + (size_t)3 * n;

    if (ws_size >= need && nbkt <= 512 && (1 << shift) <= 1024 &&
        ((size_t)n << shift) < (1u << 30)) {
        hipLaunchKernelGGL(k_chist, dim3(NHB), dim3(B), 0, stream,
                           dst, hist, e, nbkt, shift, epb);
        hipLaunchKernelGGL(k_scanA, dim3(nbkt), dim3(B), 0, stream, hist, bktCnt);
        hipLaunchKernelGGL(k_scanB, dim3(1), dim3(B), 0, stream, bktCnt, base, nbkt, e);
        hipLaunchKernelGGL(k_scatter, dim3(NHB), dim3(B), 0, stream,
                           dst, src, edge_dist, edge_feat, hist, base,
                           payA, ef_s, e, nbkt, shift, epb);
        hipLaunchKernelGGL(k_enc, dim3((n + B - 1) / B), dim3(B), 0, stream,
                           node_feat, enc_w1, enc_b1, enc_w2, enc_b2, h0, n);
        hipLaunchKernelGGL(k_passA, dim3(nbkt), dim3(B), 0, stream,
                           payA, h0, base, h1, shift, n);
        hipLaunchKernelGGL(k_passB, dim3(nbkt), dim3(B), 0, stream,
                           payA, ef_s, h1, eu_w1, eu_b1, eu_w2, eu_b2,
                           nu_w1, nu_b1, nu_w2, nu_b2, base, h2, s2, shift, n);
        hipLaunchKernelGGL(k_passC, dim3(nbkt), dim3(B), 0, stream,
                           payA, ef_s /*e2*/, h2, s2,
                           dec_w1, dec_b1, dec_w2, dec_b2, base,
                           (float*)d_out, shift, n);
    } else {
        // fallback: atomic path (needs 8n + e floats)
        float* agg  = ws + (size_t)2 * n;  // alias h2 slot
        float* s1   = ws + (size_t)4 * n;
        float* num1 = ws + (size_t)5 * n;
        float* num2 = ws + (size_t)6 * n;
        float* h2f  = ws + (size_t)7 * n;
        float* e2   = ws + (size_t)8 * n;
        hipLaunchKernelGGL(k_zero, dim3((5 * n + B - 1) / B), dim3(B), 0, stream,
                           agg, 5 * n);  // zeros agg,s2,s1,num1,num2
        hipLaunchKernelGGL(k_enc, dim3((n + B - 1) / B), dim3(B), 0, stream,
                           node_feat, enc_w1, enc_b1, enc_w2, enc_b2, h0, n);
        hipLaunchKernelGGL(k_agg1, dim3((e + B - 1) / B), dim3(B), 0, stream,
                           edge_dist, src, dst, h0, s1, num1, e);
        hipLaunchKernelGGL(k_div, dim3((n + B - 1) / B), dim3(B), 0, stream,
                           num1, s1, h1, n);
        hipLaunchKernelGGL(k_edgeF, dim3((e + B - 1) / B), dim3(B), 0, stream,
                           edge_feat, src, dst, h1, eu_w1, eu_b1, eu_w2, eu_b2,
                           e2, agg, s2, e);
        hipLaunchKernelGGL(k_nu, dim3((n + B - 1) / B), dim3(B), 0, stream,
                           agg, h1, nu_w1, nu_b1, nu_w2, nu_b2, h2f, n);
        hipLaunchKernelGGL(k_agg2F, dim3((e + B - 1) / B), dim3(B), 0, stream,
                           e2, src, dst, h2f, num2, e);
        hipLaunchKernelGGL(k_final, dim3((n + B - 1) / B), dim3(B), 0, stream,
                           num2, s2, dec_w1, dec_b1, dec_w2, dec_b2, (float*)d_out, n);
    }
}

// Round 4
// 438.752 us; speedup vs baseline: 3.7817x; 1.0989x over previous
//
#include <hip/hip_runtime.h>

// ---------------------------------------------------------------------------
// GraphElementNetwork forward, bucketed path v4:
//  - bucket by dst>>8 (bw=256, nbkt=391)
//  - each edge pass split G=4 ways per bucket (grid 1564 ~ 6 blocks/CU;
//    round-3 passB had 391 blocks -> 8.7% occupancy, latency-bound).
//    Blocks accumulate private LDS bins -> per-(bucket,slice) partials
//    (plain stores), summed by per-node finalize kernels that also carry
//    the folded node MLPs (keeps passB-main VGPR down).
// ---------------------------------------------------------------------------

#define NHB 256   // histogram / scatter blocks (1 per CU)
#define GSP 4     // slices per bucket in edge passes

// ============================ bucketing ====================================

__global__ void __launch_bounds__(256) k_chist(
    const int* __restrict__ DST, int* __restrict__ hist,
    int e, int nbkt, int shift, int epb)
{
    __shared__ int lh[512];
    for (int c = threadIdx.x; c < nbkt; c += blockDim.x) lh[c] = 0;
    __syncthreads();
    int b = blockIdx.x;
    int i0 = b * epb, i1 = min(i0 + epb, e);
    int nq = (i1 > i0) ? ((i1 - i0) >> 2) : 0;
    const int4* D4 = reinterpret_cast<const int4*>(DST + i0);
    for (int q = threadIdx.x; q < nq; q += blockDim.x) {
        int4 d = D4[q];
        atomicAdd(&lh[d.x >> shift], 1);
        atomicAdd(&lh[d.y >> shift], 1);
        atomicAdd(&lh[d.z >> shift], 1);
        atomicAdd(&lh[d.w >> shift], 1);
    }
    for (int i = i0 + 4 * nq + threadIdx.x; i < i1; i += blockDim.x)
        atomicAdd(&lh[DST[i] >> shift], 1);
    __syncthreads();
    for (int c = threadIdx.x; c < nbkt; c += blockDim.x)
        hist[(size_t)c * NHB + b] = lh[c];
}

__global__ void __launch_bounds__(256) k_scanA(
    int* __restrict__ hist, int* __restrict__ bktCnt)
{
    int c = blockIdx.x;
    int* row = hist + (size_t)c * NHB;
    __shared__ int part[256];
    int t = threadIdx.x;
    int v = row[t];
    part[t] = v;
    __syncthreads();
    for (int off = 1; off < 256; off <<= 1) {
        int x = 0;
        if (t >= off) x = part[t - off];
        __syncthreads();
        part[t] += x;
        __syncthreads();
    }
    if (t == 255) bktCnt[c] = part[255];
    row[t] = part[t] - v;
}

__global__ void __launch_bounds__(256) k_scanB(
    const int* __restrict__ bktCnt, int* __restrict__ base, int nbkt, int e)
{
    __shared__ int part[256];
    int t = threadIdx.x;
    int v[4];
    int sum = 0;
    #pragma unroll
    for (int u = 0; u < 4; ++u) {
        int idx = t * 4 + u;
        v[u] = (idx < nbkt) ? bktCnt[idx] : 0;
        sum += v[u];
    }
    part[t] = sum;
    __syncthreads();
    for (int off = 1; off < 256; off <<= 1) {
        int x = 0;
        if (t >= off) x = part[t - off];
        __syncthreads();
        part[t] += x;
        __syncthreads();
    }
    int run = (t == 0) ? 0 : part[t - 1];
    #pragma unroll
    for (int u = 0; u < 4; ++u) {
        int idx = t * 4 + u;
        if (idx < nbkt) base[idx] = run;
        run += v[u];
    }
    if (t == 0) base[nbkt] = e;
}

__global__ void __launch_bounds__(256) k_scatter(
    const int* __restrict__ DST, const int* __restrict__ SRC,
    const float* __restrict__ DIST, const float* __restrict__ EF,
    const int* __restrict__ hist, const int* __restrict__ base,
    float2* __restrict__ payA, float* __restrict__ ef_s,
    int e, int nbkt, int shift, int epb)
{
    __shared__ int loff[512];
    int b = blockIdx.x;
    for (int c = threadIdx.x; c < nbkt; c += blockDim.x)
        loff[c] = base[c] + hist[(size_t)c * NHB + b];
    __syncthreads();
    int i0 = b * epb, i1 = min(i0 + epb, e);
    if (i0 >= i1) return;
    int mask = (1 << shift) - 1;
    int nq = (i1 - i0) >> 2;
    const int4*   D4 = reinterpret_cast<const int4*>(DST + i0);
    const int4*   S4 = reinterpret_cast<const int4*>(SRC + i0);
    const float4* T4 = reinterpret_cast<const float4*>(DIST + i0);
    const float4* F4 = reinterpret_cast<const float4*>(EF + i0);
    for (int q = threadIdx.x; q < nq; q += blockDim.x) {
        int4 dv = D4[q];
        int4 sv = S4[q];
        float4 tv = T4[q];
        float4 fv = F4[q];
        #pragma unroll
        for (int u = 0; u < 4; ++u) {
            int d = (&dv.x)[u];
            int c = d >> shift;
            int pos = atomicAdd(&loff[c], 1);
            int sd = ((&sv.x)[u] << shift) | (d & mask);
            payA[pos] = make_float2(__int_as_float(sd), (&tv.x)[u]);
            ef_s[pos] = (&fv.x)[u];
        }
    }
    for (int i = i0 + 4 * nq + threadIdx.x; i < i1; i += blockDim.x) {
        int d = DST[i];
        int c = d >> shift;
        int pos = atomicAdd(&loff[c], 1);
        int sd = (SRC[i] << shift) | (d & mask);
        payA[pos] = make_float2(__int_as_float(sd), DIST[i]);
        ef_s[pos] = EF[i];
    }
}

// ============================ node encoder =================================

__global__ void __launch_bounds__(256) k_enc(
    const float* __restrict__ X, const float* __restrict__ W1,
    const float* __restrict__ B1, const float* __restrict__ W2,
    const float* __restrict__ B2, float* __restrict__ H0, int n)
{
    __shared__ float4 w1s[2048];
    for (int t = threadIdx.x; t < 2048; t += blockDim.x)
        w1s[t] = reinterpret_cast<const float4*>(W1)[t];
    __syncthreads();

    int i = blockIdx.x * blockDim.x + threadIdx.x;
    if (i >= n) return;

    const float4* xp = reinterpret_cast<const float4*>(X) + (size_t)i * 32;

    float acc[64];
    #pragma unroll
    for (int j = 0; j < 64; ++j) acc[j] = B1[j];

    for (int k4 = 0; k4 < 32; ++k4) {
        float4 xv = xp[k4];
        #pragma unroll
        for (int kk = 0; kk < 4; ++kk) {
            float x = (&xv.x)[kk];
            const float4* wrow = &w1s[(k4 * 4 + kk) * 16];
            #pragma unroll
            for (int j4 = 0; j4 < 16; ++j4) {
                float4 w = wrow[j4];
                acc[j4*4+0] = fmaf(x, w.x, acc[j4*4+0]);
                acc[j4*4+1] = fmaf(x, w.y, acc[j4*4+1]);
                acc[j4*4+2] = fmaf(x, w.z, acc[j4*4+2]);
                acc[j4*4+3] = fmaf(x, w.w, acc[j4*4+3]);
            }
        }
    }
    float o = B2[0];
    #pragma unroll
    for (int j = 0; j < 64; ++j)
        o = fmaf(fmaxf(acc[j], 0.f), W2[j], o);
    H0[i] = fmaxf(o, 0.f);
}

// ==================== bucketed edge passes (G-split) =======================
// partial layout: p[((c*GSP + g) << shift) + t]

__global__ void __launch_bounds__(256) k_passA(
    const float2* __restrict__ payA, const float* __restrict__ H0,
    const int* __restrict__ base,
    float* __restrict__ pSum, float* __restrict__ pNum, int shift)
{
    __shared__ float lsum[256], lnum[256];
    int c = blockIdx.x / GSP, g = blockIdx.x % GSP;
    int bw = 1 << shift, mask = bw - 1;
    for (int t = threadIdx.x; t < bw; t += blockDim.x) { lsum[t] = 0.f; lnum[t] = 0.f; }
    __syncthreads();
    int b0 = base[c], len = base[c + 1] - b0;
    int i0 = b0 + (int)(((long long)len * g) / GSP);
    int i1 = b0 + (int)(((long long)len * (g + 1)) / GSP);
    for (int i = i0 + threadIdx.x; i < i1; i += blockDim.x) {
        float2 pa = payA[i];
        int sd = __float_as_int(pa.x);
        float ev = __expf(pa.y);
        atomicAdd(&lsum[sd & mask], ev);
        atomicAdd(&lnum[sd & mask], ev * H0[sd >> shift]);
    }
    __syncthreads();
    size_t po = (size_t)blockIdx.x << shift;
    for (int t = threadIdx.x; t < bw; t += blockDim.x) {
        pSum[po + t] = lsum[t];
        pNum[po + t] = lnum[t];
    }
}

__global__ void __launch_bounds__(256) k_finA(
    const float* __restrict__ pSum, const float* __restrict__ pNum,
    float* __restrict__ H1, int shift, int n)
{
    int d = blockIdx.x * blockDim.x + threadIdx.x;
    if (d >= n) return;
    int c = d >> shift, t = d & ((1 << shift) - 1);
    size_t b = ((size_t)c * GSP) << shift;
    int bw = 1 << shift;
    float s = 0.f, m = 0.f;
    #pragma unroll
    for (int g = 0; g < GSP; ++g) {
        s += pSum[b + (size_t)g * bw + t];
        m += pNum[b + (size_t)g * bw + t];
    }
    H1[d] = (s != 0.f) ? m / s : 0.f;
}

// passB main: edge MLP -> e2 (overwrites ef_s) + partial agg/s2
__global__ void __launch_bounds__(256) k_passB(
    const float2* __restrict__ payA, float* __restrict__ ef_s,
    const float* __restrict__ H1,
    const float* __restrict__ W1, const float* __restrict__ B1,
    const float* __restrict__ W2, const float* __restrict__ B2,
    const int* __restrict__ base,
    float* __restrict__ pAgg, float* __restrict__ pS2, int shift, int n)
{
    __shared__ float4 wA[16], wB[16], wC[16], wD[16], wV[16];
    __shared__ float h1loc[256], lagg[256], ls2[256];
    int bw = 1 << shift, mask = bw - 1;
    int c = blockIdx.x / GSP, g = blockIdx.x % GSP;
    if (threadIdx.x < 16) {
        int j4 = threadIdx.x;
        const float4* W1v = reinterpret_cast<const float4*>(W1);
        wA[j4] = W1v[j4];
        wB[j4] = W1v[16 + j4];
        wC[j4] = W1v[32 + j4];
        wD[j4] = reinterpret_cast<const float4*>(B1)[j4];
        wV[j4] = reinterpret_cast<const float4*>(W2)[j4];
    }
    int d0 = c << shift;
    for (int t = threadIdx.x; t < bw; t += blockDim.x) {
        int d = d0 + t;
        h1loc[t] = (d < n) ? H1[d] : 0.f;
        lagg[t] = 0.f;
        ls2[t] = 0.f;
    }
    __syncthreads();
    const float b2 = B2[0];
    int b0 = base[c], len = base[c + 1] - b0;
    int i0 = b0 + (int)(((long long)len * g) / GSP);
    int i1 = b0 + (int)(((long long)len * (g + 1)) / GSP);
    const int T = blockDim.x;
    for (int i = i0 + (int)threadIdx.x; i < i1; i += 4 * T) {
        float x0[4], hs[4], hd[4], o[4];
        int lo[4], pos[4];
        bool val[4];
        #pragma unroll
        for (int u = 0; u < 4; ++u) {
            int j = i + u * T;
            val[u] = (j < i1);
            pos[u] = j;
            if (val[u]) {
                float2 pa = payA[j];
                int sd = __float_as_int(pa.x);
                lo[u] = sd & mask;
                x0[u] = ef_s[j];
                hs[u] = H1[sd >> shift];
                hd[u] = h1loc[lo[u]];
            } else { lo[u] = 0; x0[u] = 0.f; hs[u] = 0.f; hd[u] = 0.f; }
            o[u] = b2;
        }
        #pragma unroll
        for (int j4 = 0; j4 < 16; ++j4) {
            float4 a = wA[j4], b = wB[j4], cc = wC[j4], dd = wD[j4], v = wV[j4];
            #pragma unroll
            for (int u = 0; u < 4; ++u) {
                float t0 = fmaf(x0[u], a.x, fmaf(hs[u], b.x, fmaf(hd[u], cc.x, dd.x)));
                o[u] = fmaf(fmaxf(t0, 0.f), v.x, o[u]);
                float t1 = fmaf(x0[u], a.y, fmaf(hs[u], b.y, fmaf(hd[u], cc.y, dd.y)));
                o[u] = fmaf(fmaxf(t1, 0.f), v.y, o[u]);
                float t2 = fmaf(x0[u], a.z, fmaf(hs[u], b.z, fmaf(hd[u], cc.z, dd.z)));
                o[u] = fmaf(fmaxf(t2, 0.f), v.z, o[u]);
                float t3 = fmaf(x0[u], a.w, fmaf(hs[u], b.w, fmaf(hd[u], cc.w, dd.w)));
                o[u] = fmaf(fmaxf(t3, 0.f), v.w, o[u]);
            }
        }
        #pragma unroll
        for (int u = 0; u < 4; ++u) {
            if (val[u]) {
                float eh = fmaxf(o[u], 0.f);
                float ex = __expf(eh);
                ef_s[pos[u]] = ex;
                atomicAdd(&lagg[lo[u]], eh);
                atomicAdd(&ls2[lo[u]], ex);
            }
        }
    }
    __syncthreads();
    size_t po = (size_t)blockIdx.x << shift;
    for (int t = threadIdx.x; t < bw; t += blockDim.x) {
        pAgg[po + t] = lagg[t];
        pS2[po + t] = ls2[t];
    }
}

// finB: sum partials; H2 = nuMLP(agg, h1); S2
__global__ void __launch_bounds__(256) k_finB(
    const float* __restrict__ pAgg, const float* __restrict__ pS2,
    const float* __restrict__ H1,
    const float* __restrict__ NW1, const float* __restrict__ NB1,
    const float* __restrict__ NW2, const float* __restrict__ NB2,
    float* __restrict__ H2, float* __restrict__ S2, int shift, int n)
{
    int d = blockIdx.x * blockDim.x + threadIdx.x;
    if (d >= n) return;
    int c = d >> shift, t = d & ((1 << shift) - 1);
    size_t b = ((size_t)c * GSP) << shift;
    int bw = 1 << shift;
    float agg = 0.f, s2 = 0.f;
    #pragma unroll
    for (int g = 0; g < GSP; ++g) {
        agg += pAgg[b + (size_t)g * bw + t];
        s2  += pS2[b + (size_t)g * bw + t];
    }
    float xh = H1[d];
    float o = NB2[0];
    #pragma unroll
    for (int j = 0; j < 64; ++j) {
        float a = fmaf(agg, NW1[j], fmaf(xh, NW1[64 + j], NB1[j]));
        o = fmaf(fmaxf(a, 0.f), NW2[j], o);
    }
    H2[d] = fmaxf(o, 0.f);
    S2[d] = s2;
}

// passC main: partial num2
__global__ void __launch_bounds__(256) k_passC(
    const float2* __restrict__ payA, const float* __restrict__ e2_s,
    const float* __restrict__ H2, const int* __restrict__ base,
    float* __restrict__ pNum, int shift)
{
    __shared__ float lnum[256];
    int c = blockIdx.x / GSP, g = blockIdx.x % GSP;
    int bw = 1 << shift, mask = bw - 1;
    for (int t = threadIdx.x; t < bw; t += blockDim.x) lnum[t] = 0.f;
    __syncthreads();
    int b0 = base[c], len = base[c + 1] - b0;
    int i0 = b0 + (int)(((long long)len * g) / GSP);
    int i1 = b0 + (int)(((long long)len * (g + 1)) / GSP);
    for (int i = i0 + threadIdx.x; i < i1; i += blockDim.x) {
        float2 pa = payA[i];
        int sd = __float_as_int(pa.x);
        atomicAdd(&lnum[sd & mask], e2_s[i] * H2[sd >> shift]);
    }
    __syncthreads();
    size_t po = (size_t)blockIdx.x << shift;
    for (int t = threadIdx.x; t < bw; t += blockDim.x)
        pNum[po + t] = lnum[t];
}

// finC: sum partials; OUT = decMLP(num2/s2)
__global__ void __launch_bounds__(256) k_finC(
    const float* __restrict__ pNum, const float* __restrict__ S2,
    const float* __restrict__ W1, const float* __restrict__ B1,
    const float* __restrict__ W2, const float* __restrict__ B2,
    float* __restrict__ OUT, int shift, int n)
{
    int d = blockIdx.x * blockDim.x + threadIdx.x;
    if (d >= n) return;
    int c = d >> shift, t = d & ((1 << shift) - 1);
    size_t b = ((size_t)c * GSP) << shift;
    int bw = 1 << shift;
    float m = 0.f;
    #pragma unroll
    for (int g = 0; g < GSP; ++g) m += pNum[b + (size_t)g * bw + t];
    float s = S2[d];
    float x = (s != 0.f) ? m / s : 0.f;
    float o = B2[0];
    #pragma unroll
    for (int j = 0; j < 64; ++j) {
        float a = fmaf(x, W1[j], B1[j]);
        o = fmaf(fmaxf(a, 0.f), W2[j], o);
    }
    OUT[d] = fmaxf(o, 0.f);
}

// ===================== fallback (atomic path) ==============================

__device__ __forceinline__ void atomAddF(float* p, float v) { unsafeAtomicAdd(p, v); }

__global__ void k_zero(float* __restrict__ p, int n) {
    int i = blockIdx.x * blockDim.x + threadIdx.x;
    if (i < n) p[i] = 0.f;
}

__global__ void __launch_bounds__(256) k_agg1(
    const float* __restrict__ DIST, const int* __restrict__ SRC,
    const int* __restrict__ DST, const float* __restrict__ H0,
    float* __restrict__ S1, float* __restrict__ NUM1, int e)
{
    int i = blockIdx.x * blockDim.x + threadIdx.x;
    if (i >= e) return;
    float ev = __expf(DIST[i]);
    atomAddF(&S1[DST[i]], ev);
    atomAddF(&NUM1[DST[i]], ev * H0[SRC[i]]);
}

__global__ void k_div(const float* __restrict__ NUM, const float* __restrict__ S,
                      float* __restrict__ H, int n) {
    int i = blockIdx.x * blockDim.x + threadIdx.x;
    if (i < n) {
        float s = S[i];
        H[i] = (s != 0.f) ? NUM[i] / s : 0.f;
    }
}

__global__ void __launch_bounds__(256) k_edgeF(
    const float* __restrict__ EF, const int* __restrict__ SRC,
    const int* __restrict__ DST, const float* __restrict__ H1,
    const float* __restrict__ W1, const float* __restrict__ B1,
    const float* __restrict__ W2, const float* __restrict__ B2,
    float* __restrict__ E2, float* __restrict__ AGG, float* __restrict__ S2, int e)
{
    int i = blockIdx.x * blockDim.x + threadIdx.x;
    if (i >= e) return;
    float x0 = EF[i];
    int s = SRC[i], d = DST[i];
    float h_s = H1[s], h_d = H1[d];
    float o = B2[0];
    for (int j = 0; j < 64; ++j) {
        float aj = fmaf(x0, W1[j], fmaf(h_s, W1[64+j], fmaf(h_d, W1[128+j], B1[j])));
        o = fmaf(fmaxf(aj, 0.f), W2[j], o);
    }
    float eh = fmaxf(o, 0.f);
    float ex = __expf(eh);
    E2[i] = ex;
    atomAddF(&AGG[d], eh);
    atomAddF(&S2[d], ex);
}

__global__ void k_nu(const float* __restrict__ AGG, const float* __restrict__ H1,
                     const float* __restrict__ W1, const float* __restrict__ B1,
                     const float* __restrict__ W2, const float* __restrict__ B2,
                     float* __restrict__ H2, int n)
{
    int i = blockIdx.x * blockDim.x + threadIdx.x;
    if (i >= n) return;
    float x0 = AGG[i], x1 = H1[i];
    float o = B2[0];
    #pragma unroll
    for (int j = 0; j < 64; ++j) {
        float a = fmaf(x0, W1[j], fmaf(x1, W1[64 + j], B1[j]));
        o = fmaf(fmaxf(a, 0.f), W2[j], o);
    }
    H2[i] = fmaxf(o, 0.f);
}

__global__ void __launch_bounds__(256) k_agg2F(
    const float* __restrict__ E2, const int* __restrict__ SRC,
    const int* __restrict__ DST, const float* __restrict__ H2,
    float* __restrict__ NUM2, int e)
{
    int i = blockIdx.x * blockDim.x + threadIdx.x;
    if (i >= e) return;
    atomAddF(&NUM2[DST[i]], E2[i] * H2[SRC[i]]);
}

__global__ void k_final(const float* __restrict__ NUM2, const float* __restrict__ S2,
                        const float* __restrict__ W1, const float* __restrict__ B1,
                        const float* __restrict__ W2, const float* __restrict__ B2,
                        float* __restrict__ OUT, int n)
{
    int i = blockIdx.x * blockDim.x + threadIdx.x;
    if (i >= n) return;
    float s = S2[i];
    float x = (s != 0.f) ? NUM2[i] / s : 0.f;
    float o = B2[0];
    #pragma unroll
    for (int j = 0; j < 64; ++j) {
        float a = fmaf(x, W1[j], B1[j]);
        o = fmaf(fmaxf(a, 0.f), W2[j], o);
    }
    OUT[i] = fmaxf(o, 0.f);
}

// ============================ launch =======================================

extern "C" void kernel_launch(void* const* d_in, const int* in_sizes, int n_in,
                              void* d_out, int out_size, void* d_ws, size_t ws_size,
                              hipStream_t stream)
{
    const float* node_feat = (const float*)d_in[0];
    const float* edge_feat = (const float*)d_in[1];
    const float* edge_dist = (const float*)d_in[2];
    const int*   src       = (const int*)d_in[3];
    const int*   dst       = (const int*)d_in[4];
    const float* enc_w1 = (const float*)d_in[5];
    const float* enc_b1 = (const float*)d_in[6];
    const float* enc_w2 = (const float*)d_in[7];
    const float* enc_b2 = (const float*)d_in[8];
    const float* nu_w1  = (const float*)d_in[9];
    const float* nu_b1  = (const float*)d_in[10];
    const float* nu_w2  = (const float*)d_in[11];
    const float* nu_b2  = (const float*)d_in[12];
    const float* eu_w1  = (const float*)d_in[13];
    const float* eu_b1  = (const float*)d_in[14];
    const float* eu_w2  = (const float*)d_in[15];
    const float* eu_b2  = (const float*)d_in[16];
    const float* dec_w1 = (const float*)d_in[17];
    const float* dec_b1 = (const float*)d_in[18];
    const float* dec_w2 = (const float*)d_in[19];
    const float* dec_b2 = (const float*)d_in[20];

    const int n = in_sizes[0] / 128;
    const int e = in_sizes[1];
    const int B = 256;

    int shift = 8;
    while ((((n + (1 << shift) - 1) >> shift) > 512) && shift < 10) shift++;
    const int nbkt = (n + (1 << shift) - 1) >> shift;
    int epb = (e + NHB - 1) / NHB;
    epb = (epb + 3) & ~3;

    // ws layout (4B words): h0,h1,h2,s2 [4n] | base[nbkt+1] bktCnt[nbkt]
    // hist[nbkt*NHB] | pad8 | payA[2e] | ef_s[e] | pP0[nbkt*G*bw] | pP1[...]
    float* ws = (float*)d_ws;
    size_t w = (size_t)4 * n;
    int* base   = (int*)(ws + w); w += nbkt + 1;
    int* bktCnt = (int*)(ws + w); w += nbkt;
    int* hist   = (int*)(ws + w); w += (size_t)nbkt * NHB;
    w = (w + 1) & ~(size_t)1;
    float2* payA = (float2*)(ws + w); w += (size_t)2 * e;
    float* ef_s  = ws + w; w += e;
    size_t psz = ((size_t)nbkt * GSP) << shift;
    float* pP0 = ws + w; w += psz;
    float* pP1 = ws + w; w += psz;
    size_t need = w * 4;

    float* h0 = ws;
    float* h1 = ws + (size_t)1 * n;
    float* h2 = ws + (size_t)2 * n;
    float* s2 = ws + (size_t)3 * n;

    if (ws_size >= need && nbkt <= 512 && (1 << shift) <= 256 &&
        ((size_t)n << shift) < (1u << 30)) {
        const int gE = nbkt * GSP;
        hipLaunchKernelGGL(k_chist, dim3(NHB), dim3(B), 0, stream,
                           dst, hist, e, nbkt, shift, epb);
        hipLaunchKernelGGL(k_scanA, dim3(nbkt), dim3(B), 0, stream, hist, bktCnt);
        hipLaunchKernelGGL(k_scanB, dim3(1), dim3(B), 0, stream, bktCnt, base, nbkt, e);
        hipLaunchKernelGGL(k_scatter, dim3(NHB), dim3(B), 0, stream,
                           dst, src, edge_dist, edge_feat, hist, base,
                           payA, ef_s, e, nbkt, shift, epb);
        hipLaunchKernelGGL(k_enc, dim3((n + B - 1) / B), dim3(B), 0, stream,
                           node_feat, enc_w1, enc_b1, enc_w2, enc_b2, h0, n);
        hipLaunchKernelGGL(k_passA, dim3(gE), dim3(B), 0, stream,
                           payA, h0, base, pP0, pP1, shift);
        hipLaunchKernelGGL(k_finA, dim3((n + B - 1) / B), dim3(B), 0, stream,
                           pP0, pP1, h1, shift, n);
        hipLaunchKernelGGL(k_passB, dim3(gE), dim3(B), 0, stream,
                           payA, ef_s, h1, eu_w1, eu_b1, eu_w2, eu_b2, base,
                           pP0, pP1, shift, n);
        hipLaunchKernelGGL(k_finB, dim3((n + B - 1) / B), dim3(B), 0, stream,
                           pP0, pP1, h1, nu_w1, nu_b1, nu_w2, nu_b2, h2, s2, shift, n);
        hipLaunchKernelGGL(k_passC, dim3(gE), dim3(B), 0, stream,
                           payA, ef_s /*e2*/, h2, base, pP0, shift);
        hipLaunchKernelGGL(k_finC, dim3((n + B - 1) / B), dim3(B), 0, stream,
                           pP0, s2, dec_w1, dec_b1, dec_w2, dec_b2,
                           (float*)d_out, shift, n);
    } else {
        // fallback: atomic path (needs 8n + e floats)
        float* agg  = ws + (size_t)2 * n;
        float* s1   = ws + (size_t)4 * n;
        float* num1 = ws + (size_t)5 * n;
        float* num2 = ws + (size_t)6 * n;
        float* h2f  = ws + (size_t)7 * n;
        float* e2   = ws + (size_t)8 * n;
        hipLaunchKernelGGL(k_zero, dim3((5 * n + B - 1) / B), dim3(B), 0, stream,
                           agg, 5 * n);
        hipLaunchKernelGGL(k_enc, dim3((n + B - 1) / B), dim3(B), 0, stream,
                           node_feat, enc_w1, enc_b1, enc_w2, enc_b2, h0, n);
        hipLaunchKernelGGL(k_agg1, dim3((e + B - 1) / B), dim3(B), 0, stream,
                           edge_dist, src, dst, h0, s1, num1, e);
        hipLaunchKernelGGL(k_div, dim3((n + B - 1) / B), dim3(B), 0, stream,
                           num1, s1, h1, n);
        hipLaunchKernelGGL(k_edgeF, dim3((e + B - 1) / B), dim3(B), 0, stream,
                           edge_feat, src, dst, h1, eu_w1, eu_b1, eu_w2, eu_b2,
                           e2, agg, s2, e);
        hipLaunchKernelGGL(k_nu, dim3((n + B - 1) / B), dim3(B), 0, stream,
                           agg, h1, nu_w1, nu_b1, nu_w2, nu_b2, h2f, n);
        hipLaunchKernelGGL(k_agg2F, dim3((e + B - 1) / B), dim3(B), 0, stream,
                           e2, src, dst, h2f, num2, e);
        hipLaunchKernelGGL(k_final, dim3((n + B - 1) / B), dim3(B), 0, stream,
                           num2, s2, dec_w1, dec_b1, dec_w2, dec_b2, (float*)d_out, n);
    }
}